// Round 3
// baseline (271.033 us; speedup 1.0000x reference)
//
#include <hip/hip_runtime.h>

#define NEG_INF (-1e30f)
#define GUARD   (-5e29f)
#define LOG2E   1.4426950408889634f
#define LN2     0.6931471805599453f

constexpr int T = 512, N = 32, C = 4000, S = 64;
constexpr int TN = T * N;
constexpr int LPW = S + 1;     // 65: [blank, label_0..label_63] log2-probs per (t,n)
constexpr int CT = 64;         // timesteps per LDS chunk
constexpr int NCHUNK = T / CT; // 8

// Kernel 1: per (t,n) row of C=4000 logits, streaming logsumexp; emit
// log-softmax (scaled to base-2) at the 65 needed classes.
__global__ __launch_bounds__(256) void k_logsoftmax_gather(
    const float* __restrict__ x, const int* __restrict__ labels,
    float* __restrict__ lp)
{
    int row  = blockIdx.x * 4 + (threadIdx.x >> 6);   // row = t*N + n
    int lane = threadIdx.x & 63;
    const float*  rp  = x + (size_t)row * C;
    const float4* rp4 = reinterpret_cast<const float4*>(rp);

    float m = -INFINITY, s = 0.f;
    for (int i = lane; i < C / 4; i += 64) {          // 1000 float4s
        float4 v = rp4[i];
        float mv = fmaxf(fmaxf(v.x, v.y), fmaxf(v.z, v.w));
        float s4 = __expf(v.x - mv) + __expf(v.y - mv) +
                   __expf(v.z - mv) + __expf(v.w - mv);
        float nm = fmaxf(m, mv);
        s = s * __expf(m - nm) + s4 * __expf(mv - nm);
        m = nm;
    }
    for (int off = 32; off > 0; off >>= 1) {
        float om = __shfl_xor(m, off);
        float os = __shfl_xor(s, off);
        float nm = fmaxf(m, om);
        s = s * __expf(m - nm) + os * __expf(om - nm);
        m = nm;
    }
    float logZ = m + __logf(s);

    int n = row % N;
    int c = labels[n * S + lane];
    float* outp = lp + (size_t)row * LPW;
    outp[1 + lane] = (rp[c] - logZ) * LOG2E;          // base-2 domain
    if (lane == 0) outp[0] = (rp[0] - logZ) * LOG2E;
}

// DPP wave_shr:1 — value from lane-1; lane 0 gets NEG_INF via the `old` operand.
__device__ __forceinline__ float dpp_shr1_neginf(float x) {
    int r = __builtin_amdgcn_update_dpp(__float_as_int(NEG_INF),
                                        __float_as_int(x),
                                        0x138 /*wave_shr:1*/, 0xf, 0xf, false);
    return __int_as_float(r);
}

// Kernel 2: alpha recursion, one 256-thread block per batch element.
// Wave 0 runs the recursion out of LDS; waves 1-3 double-buffer the next
// 64-timestep chunk of the lp table from global into LDS.
__global__ __launch_bounds__(256) void k_ctc_alpha(
    const float* __restrict__ lp, const int* __restrict__ labels,
    const int* __restrict__ input_len, const int* __restrict__ label_len,
    float* __restrict__ loss_out)
{
    __shared__ float lds[2][CT * LPW];
    int n    = blockIdx.x;
    int tid  = threadIdx.x;
    int wv   = tid >> 6;
    int lane = tid & 63;

    // stage chunk 0 with all threads
    for (int idx = tid; idx < CT * LPW; idx += 256) {
        int t = idx / LPW, e = idx - t * LPW;
        lds[0][idx] = lp[((size_t)t * N + n) * LPW + e];
    }
    __syncthreads();

    int Tin = input_len[n];
    int Sl  = label_len[n];

    int li   = labels[n * S + lane];
    int lim1 = (lane > 0) ? labels[n * S + lane - 1] : -1;
    bool skip_ok = (lane > 0) && (li != 0) && (li != lim1);

    // t=0 init (wave 0's values are the ones that matter)
    float a0 = (lane == 0) ? lds[0][0] : NEG_INF;                    // alpha[0]
    float a1 = (lane == 0 && Sl > 0) ? lds[0][1] : NEG_INF;          // alpha[1]
    float aX = NEG_INF;                                              // alpha[128]

    for (int c = 0; c < NCHUNK; ++c) {
        int buf = c & 1;
        if (wv != 0) {
            if (c + 1 < NCHUNK) {                   // prefetch next chunk
                int t0n = (c + 1) * CT;
                for (int idx = tid - 64; idx < CT * LPW; idx += 192) {
                    int t = idx / LPW, e = idx - t * LPW;
                    lds[buf ^ 1][idx] = lp[((size_t)(t0n + t) * N + n) * LPW + e];
                }
            }
        } else {
            const float* lb = lds[buf];
            int tcs = (c == 0) ? 1 : 0;
            #pragma unroll 8
            for (int tc = tcs; tc < CT; ++tc) {
                int t = c * CT + tc;
                float cb = lb[tc * LPW];                 // blank lp (broadcast)
                float cl = lb[tc * LPW + 1 + lane];      // label lp
                float p_a1 = dpp_shr1_neginf(a1);        // alpha[2i-1]

                // even l=2i: from alpha[l], alpha[l-1]
                float m2 = fmaxf(a0, p_a1);
                float s2 = exp2f(a0 - m2) + exp2f(p_a1 - m2);
                float na0 = (m2 > GUARD) ? (m2 + log2f(s2) + cb) : NEG_INF;

                // odd l=2i+1: from alpha[l], alpha[l-1]=a0, alpha[l-2]=p_a1
                float a2v = skip_ok ? p_a1 : NEG_INF;
                float m3 = fmaxf(fmaxf(a1, a0), a2v);
                float s3 = exp2f(a1 - m3) + exp2f(a0 - m3) + exp2f(a2v - m3);
                float na1 = (m3 > GUARD) ? (m3 + log2f(s3) + cl) : NEG_INF;

                // l=128 (lane 63's value kept): from alpha[128], alpha[127]=a1
                float mX = fmaxf(aX, a1);
                float sX = exp2f(aX - mX) + exp2f(a1 - mX);
                float naX = (mX > GUARD) ? (mX + log2f(sX) + cb) : NEG_INF;

                bool act = (t < Tin);
                a0 = act ? na0 : a0;
                a1 = act ? na1 : a1;
                aX = act ? naX : aX;
            }
        }
        __syncthreads();
    }

    if (wv == 0) {
        // loss_n = -lse2(alpha[2*Sl], alpha[2*Sl-1]) * ln2
        float a_last = (Sl >= S) ? __shfl(aX, 63) : __shfl(a0, Sl);
        float a_prev_raw = __shfl(a1, (Sl > 0) ? (Sl - 1) : 0);
        float a_prev = (Sl > 0) ? a_prev_raw : NEG_INF;
        if (lane == 0) {
            float m   = fmaxf(a_last, a_prev);
            float ll2 = m + log2f(exp2f(a_last - m) + exp2f(a_prev - m));
            float loss = -ll2 * LN2;
            if (!(loss < 5e29f)) loss = 0.f;        // zero_infinity (+NaN) -> 0
            loss_out[n] = loss;
        }
    }
}

// Kernel 3: sum the N per-batch losses into d_out[0].
__global__ __launch_bounds__(64) void k_reduce(
    const float* __restrict__ loss, float* __restrict__ out)
{
    int lane = threadIdx.x;
    float v = (lane < N) ? loss[lane] : 0.f;
    for (int off = 32; off > 0; off >>= 1) v += __shfl_xor(v, off);
    if (lane == 0) out[0] = v;
}

extern "C" void kernel_launch(void* const* d_in, const int* in_sizes, int n_in,
                              void* d_out, int out_size, void* d_ws, size_t ws_size,
                              hipStream_t stream) {
    const float* x       = (const float*)d_in[0];
    const int*   labels  = (const int*)d_in[1];
    const int*   in_len  = (const int*)d_in[2];
    const int*   lab_len = (const int*)d_in[3];
    float* out  = (float*)d_out;
    float* lp   = (float*)d_ws;                        // TN*65 floats = 4.26 MB
    float* loss = lp + (size_t)TN * LPW;               // + N floats

    k_logsoftmax_gather<<<TN / 4, 256, 0, stream>>>(x, labels, lp);
    k_ctc_alpha<<<N, 256, 0, stream>>>(lp, labels, in_len, lab_len, loss);
    k_reduce<<<1, 64, 0, stream>>>(loss, out);
}

// Round 5
// 96.178 us; speedup vs baseline: 2.8180x; 2.8180x over previous
//
#include <hip/hip_runtime.h>

#define LN2 0.6931471805599453f

constexpr int T = 512, N = 32, C = 4000, S = 64;
constexpr int TN  = T * N;
constexpr int LPW = S + 1;       // 65: [blank, label_0..label_63] probs per (n,t)
constexpr int CT  = 16;          // timesteps per register prefetch chunk
constexpr int NC  = T / CT;      // 32 chunks

// ---------------- Kernel 1: softmax probabilities at the 65 needed classes ---
// One wave per (t,n) row; streaming logsumexp over C=4000; writes PROBABILITIES
// to the transposed layout pp[n][t][65] so k2 reads a contiguous per-n stream.
__global__ __launch_bounds__(256) void k_softmax_probs(
    const float* __restrict__ x, const int* __restrict__ labels,
    float* __restrict__ pp)
{
    int row  = blockIdx.x * 4 + (threadIdx.x >> 6);   // row = t*N + n
    int lane = threadIdx.x & 63;
    const float*  rp  = x + (size_t)row * C;
    const float4* rp4 = reinterpret_cast<const float4*>(rp);

    float m = -INFINITY, s = 0.f;
    for (int i = lane; i < C / 4; i += 64) {          // 1000 float4s
        float4 v = rp4[i];
        float mv = fmaxf(fmaxf(v.x, v.y), fmaxf(v.z, v.w));
        float s4 = __expf(v.x - mv) + __expf(v.y - mv) +
                   __expf(v.z - mv) + __expf(v.w - mv);
        float nm = fmaxf(m, mv);
        s = s * __expf(m - nm) + s4 * __expf(mv - nm);
        m = nm;
    }
    for (int off = 32; off; off >>= 1) {
        float om = __shfl_xor(m, off), os = __shfl_xor(s, off);
        float nm = fmaxf(m, om);
        s = s * __expf(m - nm) + os * __expf(om - nm);
        m = nm;
    }
    float logZ = m + __logf(s);

    int t = row >> 5;                                  // row / N  (N=32)
    int n = row & 31;                                  // row % N
    int c = labels[n * S + lane];
    float* outp = pp + ((size_t)n * T + t) * LPW;
    outp[1 + lane] = __expf(rp[c] - logZ);
    if (lane == 0) outp[0] = __expf(rp[0] - logZ);
}

// ---------------- DPP helpers ------------------------------------------------
// lane i <- lane i-1; lane 0 <- 0.0f (linear-domain NEG_INF)
__device__ __forceinline__ float dpp_shr1_zero(float x) {
    int r = __builtin_amdgcn_update_dpp(0, __float_as_int(x),
                                        0x138 /*wave_shr:1*/, 0xf, 0xf, false);
    return __int_as_float(r);
}
template <int CTRL>
__device__ __forceinline__ float dpp_max_step(float x) {
    int t = __builtin_amdgcn_update_dpp(__float_as_int(x), __float_as_int(x),
                                        CTRL, 0xf, 0xf, false);
    return fmaxf(x, __int_as_float(t));
}
// full-wave max, broadcast uniform via readlane(63)
__device__ __forceinline__ float wave_max_bcast(float x) {
    x = dpp_max_step<0xB1>(x);    // quad_perm [1,0,3,2]  (xor 1)
    x = dpp_max_step<0x4E>(x);    // quad_perm [2,3,0,1]  (xor 2)
    x = dpp_max_step<0x141>(x);   // row_half_mirror      (xor 4)
    x = dpp_max_step<0x140>(x);   // row_mirror           (xor 8)
    x = dpp_max_step<0x142>(x);   // row_bcast15
    x = dpp_max_step<0x143>(x);   // row_bcast31 -> lane 63 has wave max
    return __int_as_float(__builtin_amdgcn_readlane(__float_as_int(x), 63));
}
// rescale alphas so the wave max sits near 2^100.
// v_ldexp_f32 per value: exact power-of-2 scale, safe for any k (no inf*0).
__device__ __forceinline__ void renorm(float& a0, float& a1, float& aX, int& SH) {
    float g = wave_max_bcast(fmaxf(a0, fmaxf(a1, aX)));
    unsigned bits = __float_as_uint(g);
    int e = (bits == 0u) ? 100 : (int)(bits >> 23) - 127;  // zero -> k=0
    int k = 100 - e;
    a0 = ldexpf(a0, k);
    a1 = ldexpf(a1, k);
    aX = ldexpf(aX, k);
    SH += k;
}

#define LOADC(CB, CL, cc) do {                                             \
    const float* cp_ = bp + (size_t)(cc) * (CT * LPW);                     \
    _Pragma("unroll")                                                      \
    for (int d_ = 0; d_ < CT; ++d_) {                                      \
        CB[d_] = cp_[d_ * LPW];                                            \
        CL[d_] = cp_[d_ * LPW + 1 + lane];                                 \
    } } while (0)

#define COMPC(CB, CL, cc) do {                                             \
    int tb_ = (cc) * CT;                                                   \
    _Pragma("unroll")                                                      \
    for (int d_ = 0; d_ < CT; ++d_) {                                      \
        int t_ = tb_ + d_;                                                 \
        bool act_ = (unsigned)(t_ - 1) < (unsigned)(Tin - 1);              \
        float cb_ = CB[d_], cl_ = CL[d_];                                  \
        float p1_ = dpp_shr1_zero(a1);          /* alpha[2i-1] */          \
        float na0_ = (a0 + p1_) * cb_;          /* blank pos 2i */         \
        float ts_  = a0 + a1 + (skip_ok ? p1_ : 0.f);                      \
        float na1_ = ts_ * cl_;                 /* label pos 2i+1 */       \
        float naX_ = (aX + a1) * cb_;           /* pos 128 (lane 63) */    \
        a0 = act_ ? na0_ : a0;                                             \
        a1 = act_ ? na1_ : a1;                                             \
        aX = act_ ? naX_ : aX;                                             \
        if ((d_ & 3) == 3) renorm(a0, a1, aX, SH);                         \
    } } while (0)

// ---------------- Kernel 2: alpha recursion, linear domain ------------------
// One wave per batch element. Lane i owns lattice positions 2i, 2i+1; lane 63
// also owns 128. Register-double-buffered 16-step chunks; no LDS, no barriers.
__global__ __launch_bounds__(64) void k_ctc_alpha(
    const float* __restrict__ pp, const int* __restrict__ labels,
    const int* __restrict__ input_len, const int* __restrict__ label_len,
    float* __restrict__ loss_out)
{
    int n = blockIdx.x, lane = threadIdx.x;
    const float* bp = pp + (size_t)n * T * LPW;
    int Tin = input_len[n], Sl = label_len[n];

    int li   = labels[n * S + lane];
    int lim1 = lane ? labels[n * S + lane - 1] : -1;
    bool skip_ok = (lane > 0) && (li != 0) && (li != lim1);

    float v0 = bp[0], v1 = bp[1];
    float a0 = (lane == 0) ? v0 : 0.f;                 // alpha[0] (prob domain)
    float a1 = (lane == 0 && Sl > 0) ? v1 : 0.f;       // alpha[1]
    float aX = 0.f;                                    // alpha[128]
    int   SH = 0;                                      // accumulated log2 shift

    float cbA[CT], clA[CT], cbB[CT], clB[CT];
    LOADC(cbA, clA, 0);
    LOADC(cbB, clB, 1);
    for (int c = 0; c < NC; c += 2) {
        COMPC(cbA, clA, c);
        if (c + 2 < NC) LOADC(cbA, clA, c + 2);
        COMPC(cbB, clB, c + 1);
        if (c + 3 < NC) LOADC(cbB, clB, c + 3);
    }

    float a_last = (Sl >= S) ? __shfl(aX, 63) : __shfl(a0, Sl);
    float a_prev_raw = __shfl(a1, (Sl > 0) ? (Sl - 1) : 0);
    float a_prev = (Sl > 0) ? a_prev_raw : 0.f;
    if (lane == 0) {
        float sum  = a_last + a_prev;
        float ll2  = log2f(sum) - (float)SH;           // log2 P
        float loss = -ll2 * LN2;
        if (!(loss < 5e29f)) loss = 0.f;               // zero_infinity (+NaN)
        loss_out[n] = loss;
    }
}

// ---------------- Kernel 3: final sum ---------------------------------------
__global__ __launch_bounds__(64) void k_reduce(
    const float* __restrict__ loss, float* __restrict__ out)
{
    int lane = threadIdx.x;
    float v = (lane < N) ? loss[lane] : 0.f;
    for (int off = 32; off; off >>= 1) v += __shfl_xor(v, off);
    if (lane == 0) out[0] = v;
}

extern "C" void kernel_launch(void* const* d_in, const int* in_sizes, int n_in,
                              void* d_out, int out_size, void* d_ws, size_t ws_size,
                              hipStream_t stream) {
    const float* x       = (const float*)d_in[0];
    const int*   labels  = (const int*)d_in[1];
    const int*   in_len  = (const int*)d_in[2];
    const int*   lab_len = (const int*)d_in[3];
    float* out  = (float*)d_out;
    float* pp   = (float*)d_ws;                        // TN*65 floats = 4.26 MB
    float* loss = pp + (size_t)TN * LPW;               // + N floats

    k_softmax_probs<<<TN / 4, 256, 0, stream>>>(x, labels, pp);
    k_ctc_alpha<<<N, 64, 0, stream>>>(pp, labels, in_len, lab_len, loss);
    k_reduce<<<1, 64, 0, stream>>>(loss, out);
}